// Round 1
// 860.135 us; speedup vs baseline: 1.3819x; 1.3819x over previous
//
#include <hip/hip_runtime.h>
#include <hip/hip_bf16.h>
#include <math.h>

#define BN    32
#define NTOK  785
#define GH    28
#define GW    28
#define DIM   768
#define QKVD  2304
#define NH    8
#define HD    96
#define MROWS (BN*NTOK)   // 25120

typedef __hip_bfloat16 bf16;
typedef unsigned short ushort_t;
typedef short s16x8 __attribute__((ext_vector_type(8)));   // 8 bf16 = 4 VGPRs
typedef float f32x4 __attribute__((ext_vector_type(4)));   // MFMA acc

// ---------------------------------------------------------------------------
// helpers
// ---------------------------------------------------------------------------
__device__ __forceinline__ void gl2lds16(const void* g, void* l) {
    // 16B per lane, LDS dest = wave-uniform base + lane*16
    __builtin_amdgcn_global_load_lds(
        (__attribute__((address_space(1))) void*)const_cast<void*>(g),
        (__attribute__((address_space(3))) void*)l, 16, 0, 0);
}

__device__ __forceinline__ ushort_t f2bf(float f) {
    bf16 h = __float2bfloat16(f);
    return *(ushort_t*)&h;
}

// ---------------------------------------------------------------------------
// K-1: fp32 -> bf16 convert (x -> xb). 8 elems/thread, vectorized.
// ---------------------------------------------------------------------------
__global__ __launch_bounds__(256)
void f32_to_bf16_kernel(const float* __restrict__ in, ushort_t* __restrict__ out,
                        int n8) {
    int i = blockIdx.x * 256 + threadIdx.x;
    if (i >= n8) return;
    const float4* p = (const float4*)(in + (size_t)i * 8);
    float4 a = p[0], b = p[1];
    union { s16x8 v; __hip_bfloat162 h[4]; } r;
    r.h[0] = __float22bfloat162_rn(make_float2(a.x, a.y));
    r.h[1] = __float22bfloat162_rn(make_float2(a.z, a.w));
    r.h[2] = __float22bfloat162_rn(make_float2(b.x, b.y));
    r.h[3] = __float22bfloat162_rn(make_float2(b.z, b.w));
    *(s16x8*)(out + (size_t)i * 8) = r.v;
}

// ---------------------------------------------------------------------------
// K0: transpose-convert W[R][C] fp32 -> Wt[C][R] bf16
// ---------------------------------------------------------------------------
__global__ __launch_bounds__(256)
void transpose_bf16_kernel(const float* __restrict__ W, ushort_t* __restrict__ Wt,
                           int R, int C) {
    __shared__ float tile[32][33];
    int c0 = blockIdx.x * 32, r0 = blockIdx.y * 32;
    int tx = threadIdx.x, ty = threadIdx.y;   // 32 x 8
    #pragma unroll
    for (int i = 0; i < 4; ++i)
        tile[ty + i * 8][tx] = W[(size_t)(r0 + ty + i * 8) * C + c0 + tx];
    __syncthreads();
    #pragma unroll
    for (int i = 0; i < 4; ++i)
        Wt[(size_t)(c0 + ty + i * 8) * R + r0 + tx] = f2bf(tile[tx][ty + i * 8]);
}

// ---------------------------------------------------------------------------
// K1: qkv GEMM via MFMA. A = xb bf16 [M][768], Bt = W_qkv^T bf16 [2304][768].
// 128x128 tile, BK=32, 4 waves, 16x16x32 MFMA.
// LDS tiles [128 rows][32 cols] bf16 (64B rows = 4 x 16B slots), XOR-swizzled:
//   slot' = slot ^ ((row>>1)&3)
// Staging keeps LDS linear (global_load_lds) and pre-swizzles the GLOBAL
// source slot: slot_g = (lane&3) ^ ((lane>>3)&3)  (rule #21: both-sides).
// Read applies the same involution: slot' = q4 ^ ((l15>>1)&3)  -> 2-way banks.
// ---------------------------------------------------------------------------
__global__ __launch_bounds__(256)
void gemm_qkv_mfma(const ushort_t* __restrict__ A, const ushort_t* __restrict__ Bt,
                   const float* __restrict__ bias,
                   ushort_t* __restrict__ q, ushort_t* __restrict__ kk,
                   ushort_t* __restrict__ v) {
    const int M = MROWS, K = DIM;
    __shared__ ushort_t Asm[128 * 32];   // 8 KB
    __shared__ ushort_t Bsm[128 * 32];   // 8 KB
    const int tid  = threadIdx.x;
    const int wave = tid >> 6;
    const int lane = tid & 63;
    const int row0 = blockIdx.y * 128;
    const int col0 = blockIdx.x * 128;
    const int wm = wave >> 1, wn = wave & 1;
    const int q4 = lane >> 4, l15 = lane & 15;
    const int slotg = (lane & 3) ^ ((lane >> 3) & 3);  // staging source slot
    const int swz   = (l15 >> 1) & 3;                  // read-side row xor

    f32x4 acc[4][4];
    #pragma unroll
    for (int i = 0; i < 4; ++i)
        #pragma unroll
        for (int j = 0; j < 4; ++j) acc[i][j] = (f32x4){0.f, 0.f, 0.f, 0.f};

    for (int kt = 0; kt < K; kt += 32) {
        #pragma unroll
        for (int r = 0; r < 2; ++r) {
            int seg = r * 4 + wave;
            int rit = seg * 16 + (lane >> 2);
            int grow = min(row0 + rit, M - 1);
            const ushort_t* gp = A + (size_t)grow * K + kt + slotg * 8;
            gl2lds16(gp, &Asm[seg * 512]);
        }
        #pragma unroll
        for (int r = 0; r < 2; ++r) {
            int seg = r * 4 + wave;
            int nit = seg * 16 + (lane >> 2);
            const ushort_t* gp = Bt + (size_t)(col0 + nit) * K + kt + slotg * 8;
            gl2lds16(gp, &Bsm[seg * 512]);
        }
        __syncthreads();
        s16x8 af[4], bfr[4];
        #pragma unroll
        for (int mi = 0; mi < 4; ++mi)
            af[mi] = *(const s16x8*)&Asm[(wm * 64 + mi * 16 + l15) * 32
                                         + ((q4 ^ swz) * 8)];
        #pragma unroll
        for (int ni = 0; ni < 4; ++ni)
            bfr[ni] = *(const s16x8*)&Bsm[(wn * 64 + ni * 16 + l15) * 32
                                          + ((q4 ^ swz) * 8)];
        #pragma unroll
        for (int mi = 0; mi < 4; ++mi)
            #pragma unroll
            for (int ni = 0; ni < 4; ++ni)
                acc[mi][ni] = __builtin_amdgcn_mfma_f32_16x16x32_bf16(
                    af[mi], bfr[ni], acc[mi][ni], 0, 0, 0);
        __syncthreads();
    }
    int colbase = col0 + wn * 64;
    int seg = colbase / DIM;
    int csub = colbase - seg * DIM;
    ushort_t* outp = (seg == 0) ? q : (seg == 1) ? kk : v;
    #pragma unroll
    for (int mi = 0; mi < 4; ++mi) {
        #pragma unroll
        for (int ni = 0; ni < 4; ++ni) {
            int gcol = colbase + ni * 16 + l15;
            int col  = csub + ni * 16 + l15;
            float bb = bias[gcol];
            #pragma unroll
            for (int j = 0; j < 4; ++j) {
                int row = row0 + wm * 64 + mi * 16 + q4 * 4 + j;
                if (row < M)
                    outp[(size_t)row * DIM + col] = f2bf(acc[mi][ni][j] + bb);
            }
        }
    }
}

// ---------------------------------------------------------------------------
// K6: out GEMM via MFMA. A = o bf16, Bt = W_out^T bf16, C fp32.
// Same swizzled-LDS structure as K1.
// ---------------------------------------------------------------------------
__global__ __launch_bounds__(256)
void gemm_out_mfma(const ushort_t* __restrict__ A, const ushort_t* __restrict__ Bt,
                   const float* __restrict__ bias, float* __restrict__ C) {
    const int M = MROWS, N = DIM, K = DIM;
    __shared__ ushort_t Asm[128 * 32];
    __shared__ ushort_t Bsm[128 * 32];
    const int tid  = threadIdx.x;
    const int wave = tid >> 6;
    const int lane = tid & 63;
    const int row0 = blockIdx.y * 128;
    const int col0 = blockIdx.x * 128;
    const int wm = wave >> 1, wn = wave & 1;
    const int q4 = lane >> 4, l15 = lane & 15;
    const int slotg = (lane & 3) ^ ((lane >> 3) & 3);
    const int swz   = (l15 >> 1) & 3;

    f32x4 acc[4][4];
    #pragma unroll
    for (int i = 0; i < 4; ++i)
        #pragma unroll
        for (int j = 0; j < 4; ++j) acc[i][j] = (f32x4){0.f, 0.f, 0.f, 0.f};

    for (int kt = 0; kt < K; kt += 32) {
        #pragma unroll
        for (int r = 0; r < 2; ++r) {
            int seg = r * 4 + wave;
            int rit = seg * 16 + (lane >> 2);
            int grow = min(row0 + rit, M - 1);
            const ushort_t* gp = A + (size_t)grow * K + kt + slotg * 8;
            gl2lds16(gp, &Asm[seg * 512]);
        }
        #pragma unroll
        for (int r = 0; r < 2; ++r) {
            int seg = r * 4 + wave;
            int nit = seg * 16 + (lane >> 2);
            const ushort_t* gp = Bt + (size_t)(col0 + nit) * K + kt + slotg * 8;
            gl2lds16(gp, &Bsm[seg * 512]);
        }
        __syncthreads();
        s16x8 af[4], bfr[4];
        #pragma unroll
        for (int mi = 0; mi < 4; ++mi)
            af[mi] = *(const s16x8*)&Asm[(wm * 64 + mi * 16 + l15) * 32
                                         + ((q4 ^ swz) * 8)];
        #pragma unroll
        for (int ni = 0; ni < 4; ++ni)
            bfr[ni] = *(const s16x8*)&Bsm[(wn * 64 + ni * 16 + l15) * 32
                                          + ((q4 ^ swz) * 8)];
        #pragma unroll
        for (int mi = 0; mi < 4; ++mi)
            #pragma unroll
            for (int ni = 0; ni < 4; ++ni)
                acc[mi][ni] = __builtin_amdgcn_mfma_f32_16x16x32_bf16(
                    af[mi], bfr[ni], acc[mi][ni], 0, 0, 0);
        __syncthreads();
    }
    #pragma unroll
    for (int mi = 0; mi < 4; ++mi) {
        #pragma unroll
        for (int ni = 0; ni < 4; ++ni) {
            int col = col0 + wn * 64 + ni * 16 + l15;
            float bb = bias[col];
            #pragma unroll
            for (int j = 0; j < 4; ++j) {
                int row = row0 + wm * 64 + mi * 16 + q4 * 4 + j;
                if (row < M)
                    C[(size_t)row * N + col] = acc[mi][ni][j] + bb;
            }
        }
    }
}

// ---------------------------------------------------------------------------
// K2: per-(b,c) softmax stats over 785 tokens of k
// ---------------------------------------------------------------------------
__global__ __launch_bounds__(256)
void softmax_stats_kernel(const bf16* __restrict__ k,
                          float* __restrict__ stat_m, float* __restrict__ stat_is) {
    int b = blockIdx.y;
    int c = blockIdx.x * 64 + threadIdx.x;
    int ty = threadIdx.y;
    const bf16* base = k + (size_t)b * NTOK * DIM + c;
    float m = -1e30f, s = 0.f;
    for (int n = ty; n < NTOK; n += 4) {
        float kv = __bfloat162float(base[(size_t)n * DIM]);
        float nm = fmaxf(m, kv);
        s = s * __expf(m - nm) + __expf(kv - nm);
        m = nm;
    }
    __shared__ float sm[4][64], ss[4][64];
    sm[ty][threadIdx.x] = m; ss[ty][threadIdx.x] = s;
    __syncthreads();
    if (ty == 0) {
        float M = sm[0][threadIdx.x];
        #pragma unroll
        for (int i = 1; i < 4; ++i) M = fmaxf(M, sm[i][threadIdx.x]);
        float S = 0.f;
        #pragma unroll
        for (int i = 0; i < 4; ++i) S += ss[i][threadIdx.x] * __expf(sm[i][threadIdx.x] - M);
        stat_m[b * DIM + c] = M;
        stat_is[b * DIM + c] = 1.f / S;
    }
}

// ---------------------------------------------------------------------------
// K3: attn[b,h,d,e] = sum_n softmax(k)[n,d] * v[n,e]
// ---------------------------------------------------------------------------
__global__ __launch_bounds__(256)
void attn_kernel(const bf16* __restrict__ k, const bf16* __restrict__ v,
                 const float* __restrict__ stat_m, const float* __restrict__ stat_is,
                 float* __restrict__ attn) {
    int h = blockIdx.x, b = blockIdx.y;
    int tx = threadIdx.x, ty = threadIdx.y;
    int t = ty * 16 + tx;
    __shared__ float ek[16][96], vv[16][96];
    __shared__ float smM[96], smIS[96];
    if (t < 96) { smM[t] = stat_m[b * DIM + h * HD + t]; smIS[t] = stat_is[b * DIM + h * HD + t]; }
    __syncthreads();
    float acc[6][6] = {};
    const bf16* kbase = k + (size_t)b * NTOK * DIM + h * HD;
    const bf16* vbase = v + (size_t)b * NTOK * DIM + h * HD;
    for (int n0 = 0; n0 < NTOK; n0 += 16) {
        #pragma unroll
        for (int i = 0; i < 6; ++i) {
            int idx = t + i * 256;
            int nl = idx / 96, c = idx % 96;
            int n = n0 + nl;
            float ekv = 0.f, vvv = 0.f;
            if (n < NTOK) {
                float kv = __bfloat162float(kbase[(size_t)n * DIM + c]);
                ekv = __expf(kv - smM[c]) * smIS[c];
                vvv = __bfloat162float(vbase[(size_t)n * DIM + c]);
            }
            ek[nl][c] = ekv; vv[nl][c] = vvv;
        }
        __syncthreads();
        #pragma unroll
        for (int nl = 0; nl < 16; ++nl) {
            float ka[6], vb[6];
            #pragma unroll
            for (int i = 0; i < 6; ++i) ka[i] = ek[nl][tx * 6 + i];
            #pragma unroll
            for (int j = 0; j < 6; ++j) vb[j] = vv[nl][ty * 6 + j];
            #pragma unroll
            for (int i = 0; i < 6; ++i)
                #pragma unroll
                for (int j = 0; j < 6; ++j)
                    acc[i][j] += ka[i] * vb[j];
        }
        __syncthreads();
    }
    float* abase = attn + ((size_t)(b * NH + h)) * HD * HD;
    #pragma unroll
    for (int i = 0; i < 6; ++i)
        #pragma unroll
        for (int j = 0; j < 6; ++j)
            abase[(size_t)(tx * 6 + i) * HD + ty * 6 + j] = acc[i][j];
}

// ---------------------------------------------------------------------------
// K4: CRPE depthwise conv, LDS-staged. Block = (cgroup64, half, batch).
// ---------------------------------------------------------------------------
template<int KS>
__device__ __forceinline__ void crpe_conv(const ushort_t* vimg, const float* wp,
                                          float bias0, float bias1,
                                          ushort_t* ob, int chp, int yq,
                                          int hf, int rowlo) {
    constexpr int R = KS / 2;
    float wA[KS * KS], wB[KS * KS];
    #pragma unroll
    for (int i = 0; i < KS * KS; ++i) { wA[i] = wp[i]; wB[i] = wp[KS * KS + i]; }
    #pragma unroll
    for (int yy0 = 0; yy0 < 2; ++yy0) {
        int yl = yq + yy0 * 8;
        if (yl >= 14) break;
        int y = hf * 14 + yl;
        for (int x = 0; x < GW; ++x) {
            float a0 = bias0, a1 = bias1;
            #pragma unroll
            for (int ky = 0; ky < KS; ++ky) {
                int gy = y + ky - R;
                if (gy < 0 || gy >= GH) continue;
                int ly = gy - rowlo;
                #pragma unroll
                for (int kx = 0; kx < KS; ++kx) {
                    int xx = x + kx - R;
                    if (xx < 0 || xx >= GW) continue;
                    __hip_bfloat162 pv =
                        *(const __hip_bfloat162*)&vimg[(ly * 28 + xx) * 64 + chp * 2];
                    float2 f = __bfloat1622float2(pv);
                    a0 = fmaf(wA[ky * KS + kx], f.x, a0);
                    a1 = fmaf(wB[ky * KS + kx], f.y, a1);
                }
            }
            *(__hip_bfloat162*)&ob[(size_t)(1 + y * GW + x) * DIM + chp * 2] =
                __float22bfloat162_rn(make_float2(a0, a1));
        }
    }
}

__global__ __launch_bounds__(256)
void crpe_lds_kernel(const ushort_t* __restrict__ v,
                     const float* __restrict__ w3, const float* __restrict__ b3,
                     const float* __restrict__ w5, const float* __restrict__ b5,
                     const float* __restrict__ w7, const float* __restrict__ b7,
                     ushort_t* __restrict__ o) {
    __shared__ ushort_t vimg[17 * 28 * 64];   // 60928 B
    const int cg  = blockIdx.x;    // 0..11 channel group
    const int hf  = blockIdx.y;    // 0..1 image half
    const int b   = blockIdx.z;
    const int tid = threadIdx.x;
    const int c0  = cg * 64;
    const int rowlo = hf ? 11 : 0;     // staged global rows rowlo..rowlo+16

    const ushort_t* vb = v + (size_t)b * NTOK * DIM + c0;
    for (int idx = tid; idx < 17 * 28 * 8; idx += 256) {
        int p8 = idx >> 3, c8 = idx & 7;
        int pix = rowlo * 28 + p8;     // global pixel (row-major, contiguous)
        *(s16x8*)&vimg[p8 * 64 + c8 * 8] =
            *(const s16x8*)(vb + (size_t)(1 + pix) * DIM + c8 * 8);
    }
    ushort_t* ob = o + (size_t)b * NTOK * DIM + c0;
    if (hf == 0 && tid < 64) ob[tid] = 0;   // CLS row: rp = 0 (bf16 zero bits)
    __syncthreads();

    const int chp = tid & 31;      // channel pair within group
    const int yq  = tid >> 5;      // 0..7 row phase
    const int ch0 = c0 + chp * 2;
    if (ch0 < 192)
        crpe_conv<3>(vimg, w3 + ch0 * 9, b3[ch0], b3[ch0 + 1], ob, chp, yq, hf, rowlo);
    else if (ch0 < 480)
        crpe_conv<5>(vimg, w5 + (ch0 - 192) * 25, b5[ch0 - 192], b5[ch0 - 191],
                     ob, chp, yq, hf, rowlo);
    else
        crpe_conv<7>(vimg, w7 + (ch0 - 480) * 49, b7[ch0 - 480], b7[ch0 - 479],
                     ob, chp, yq, hf, rowlo);
}

// ---------------------------------------------------------------------------
// K5: o[b,n,h*96+e] = scale * sum_d q[n,d] attn[d,e] + q[n,e] * rp (in-place)
// ---------------------------------------------------------------------------
__global__ __launch_bounds__(256)
void combine_kernel(const bf16* __restrict__ q, const float* __restrict__ attn,
                    bf16* __restrict__ o) {
    int h = blockIdx.x;
    int n0 = blockIdx.y * 64;
    int b = blockIdx.z;
    int tx = threadIdx.x, ty = threadIdx.y;
    int t = ty * 16 + tx;
    __shared__ float as[96][96];
    __shared__ float qs[64][97];
    const float* abase = attn + ((size_t)(b * NH + h)) * HD * HD;
    #pragma unroll
    for (int i = 0; i < 36; ++i) {
        int idx = t + i * 256;
        as[idx / 96][idx % 96] = abase[idx];
    }
    const bf16* qbase = q + (size_t)b * NTOK * DIM + h * HD;
    #pragma unroll
    for (int i = 0; i < 24; ++i) {
        int idx = t + i * 256;
        int rr = idx / 96, cc = idx % 96;
        int n = n0 + rr;
        qs[rr][cc] = (n < NTOK) ? __bfloat162float(qbase[(size_t)n * DIM + cc]) : 0.f;
    }
    __syncthreads();
    float acc[4][6] = {};
    for (int d = 0; d < 96; ++d) {
        float qa[4], ab[6];
        #pragma unroll
        for (int i = 0; i < 4; ++i) qa[i] = qs[ty * 4 + i][d];
        #pragma unroll
        for (int j = 0; j < 6; ++j) ab[j] = as[d][tx * 6 + j];
        #pragma unroll
        for (int i = 0; i < 4; ++i)
            #pragma unroll
            for (int j = 0; j < 6; ++j)
                acc[i][j] += qa[i] * ab[j];
    }
    const float scale = 0.10206207261596575f;  // 96^-0.5
    bf16* obase = o + (size_t)b * NTOK * DIM + h * HD;
    #pragma unroll
    for (int i = 0; i < 4; ++i) {
        int n = n0 + ty * 4 + i;
        if (n >= NTOK) continue;
        #pragma unroll
        for (int j = 0; j < 6; ++j) {
            int e = tx * 6 + j;
            size_t oa = (size_t)n * DIM + e;
            float rp = __bfloat162float(obase[oa]);
            float qv = qs[ty * 4 + i][e];
            obase[oa] = __float2bfloat16(scale * acc[i][j] + qv * rp);
        }
    }
}

// ---------------------------------------------------------------------------
extern "C" void kernel_launch(void* const* d_in, const int* in_sizes, int n_in,
                              void* d_out, int out_size, void* d_ws, size_t ws_size,
                              hipStream_t stream) {
    const float* x     = (const float*)d_in[0];
    const float* W_qkv = (const float*)d_in[1];
    const float* b_qkv = (const float*)d_in[2];
    const float* W_out = (const float*)d_in[3];
    const float* b_out = (const float*)d_in[4];
    const float* w3    = (const float*)d_in[5];
    const float* cb3   = (const float*)d_in[6];
    const float* w5    = (const float*)d_in[7];
    const float* cb5   = (const float*)d_in[8];
    const float* w7    = (const float*)d_in[9];
    const float* cb7   = (const float*)d_in[10];
    float* out = (float*)d_out;

    ushort_t* q = (ushort_t*)d_ws;
    ushort_t* k = q + (size_t)MROWS * DIM;
    ushort_t* v = k + (size_t)MROWS * DIM;
    float* attn    = (float*)(v + (size_t)MROWS * DIM);
    float* stat_m  = attn + (size_t)BN * NH * HD * HD;
    float* stat_is = stat_m + (size_t)BN * DIM;
    ushort_t* Wqkvt = (ushort_t*)(stat_is + (size_t)BN * DIM);
    ushort_t* Wot   = Wqkvt + (size_t)QKVD * DIM;
    ushort_t* o = k;   // alias: k dead after attn_kernel

    // xb (bf16 x) aliases d_out: 25120*768*2 B = 38.6 MB <= out 77 MB fp32.
    // Dead before gemm_out_mfma writes d_out.
    ushort_t* xb = (ushort_t*)d_out;

    transpose_bf16_kernel<<<dim3(QKVD / 32, DIM / 32), dim3(32, 8), 0, stream>>>(
        W_qkv, Wqkvt, DIM, QKVD);
    transpose_bf16_kernel<<<dim3(DIM / 32, DIM / 32), dim3(32, 8), 0, stream>>>(
        W_out, Wot, DIM, DIM);
    {
        int n8 = MROWS * DIM / 8;
        f32_to_bf16_kernel<<<dim3((n8 + 255) / 256), 256, 0, stream>>>(x, xb, n8);
    }
    gemm_qkv_mfma<<<dim3(QKVD / 128, (MROWS + 127) / 128), 256, 0, stream>>>(
        xb, Wqkvt, b_qkv, q, k, v);
    softmax_stats_kernel<<<dim3(12, BN), dim3(64, 4), 0, stream>>>(
        (const bf16*)k, stat_m, stat_is);
    attn_kernel<<<dim3(NH, BN), dim3(16, 16), 0, stream>>>(
        (const bf16*)k, (const bf16*)v, stat_m, stat_is, attn);
    crpe_lds_kernel<<<dim3(12, 2, BN), 256, 0, stream>>>(
        v, w3, cb3, w5, cb5, w7, cb7, o);
    combine_kernel<<<dim3(NH, 13, BN), dim3(16, 16), 0, stream>>>(
        (const bf16*)q, attn, (bf16*)o);
    gemm_out_mfma<<<dim3(DIM / 128, (MROWS + 127) / 128), 256, 0, stream>>>(
        o, Wot, b_out, out);
}

// Round 2
// 750.071 us; speedup vs baseline: 1.5846x; 1.1467x over previous
//
#include <hip/hip_runtime.h>
#include <hip/hip_bf16.h>
#include <math.h>

#define BN    32
#define NTOK  785
#define GH    28
#define GW    28
#define DIM   768
#define QKVD  2304
#define NH    8
#define HD    96
#define MROWS (BN*NTOK)   // 25120

typedef __hip_bfloat16 bf16;
typedef unsigned short ushort_t;
typedef short s16x8 __attribute__((ext_vector_type(8)));   // 8 bf16 = 4 VGPRs
typedef float f32x4 __attribute__((ext_vector_type(4)));   // MFMA acc

// ---------------------------------------------------------------------------
// helpers
// ---------------------------------------------------------------------------
__device__ __forceinline__ void gl2lds16(const void* g, void* l) {
    // 16B per lane, LDS dest = wave-uniform base + lane*16
    __builtin_amdgcn_global_load_lds(
        (__attribute__((address_space(1))) void*)const_cast<void*>(g),
        (__attribute__((address_space(3))) void*)l, 16, 0, 0);
}

__device__ __forceinline__ ushort_t f2bf(float f) {
    bf16 h = __float2bfloat16(f);
    return *(ushort_t*)&h;
}

// ---------------------------------------------------------------------------
// K-1: fp32 -> bf16 convert (x -> xb). 8 elems/thread, vectorized.
// ---------------------------------------------------------------------------
__global__ __launch_bounds__(256)
void f32_to_bf16_kernel(const float* __restrict__ in, ushort_t* __restrict__ out,
                        int n8) {
    int i = blockIdx.x * 256 + threadIdx.x;
    if (i >= n8) return;
    const float4* p = (const float4*)(in + (size_t)i * 8);
    float4 a = p[0], b = p[1];
    union { s16x8 v; __hip_bfloat162 h[4]; } r;
    r.h[0] = __float22bfloat162_rn(make_float2(a.x, a.y));
    r.h[1] = __float22bfloat162_rn(make_float2(a.z, a.w));
    r.h[2] = __float22bfloat162_rn(make_float2(b.x, b.y));
    r.h[3] = __float22bfloat162_rn(make_float2(b.z, b.w));
    *(s16x8*)(out + (size_t)i * 8) = r.v;
}

// ---------------------------------------------------------------------------
// K0: transpose-convert W[R][C] fp32 -> Wt[C][R] bf16
// ---------------------------------------------------------------------------
__global__ __launch_bounds__(256)
void transpose_bf16_kernel(const float* __restrict__ W, ushort_t* __restrict__ Wt,
                           int R, int C) {
    __shared__ float tile[32][33];
    int c0 = blockIdx.x * 32, r0 = blockIdx.y * 32;
    int tx = threadIdx.x, ty = threadIdx.y;   // 32 x 8
    #pragma unroll
    for (int i = 0; i < 4; ++i)
        tile[ty + i * 8][tx] = W[(size_t)(r0 + ty + i * 8) * C + c0 + tx];
    __syncthreads();
    #pragma unroll
    for (int i = 0; i < 4; ++i)
        Wt[(size_t)(c0 + ty + i * 8) * R + r0 + tx] = f2bf(tile[tx][ty + i * 8]);
}

// ---------------------------------------------------------------------------
// K1: qkv GEMM via MFMA. A = xb bf16 [M][768], Bt = W_qkv^T bf16 [2304][768].
// 128x128 tile, BK=32, 4 waves, 16x16x32 MFMA. XOR-swizzled LDS (see r0).
// ---------------------------------------------------------------------------
__global__ __launch_bounds__(256)
void gemm_qkv_mfma(const ushort_t* __restrict__ A, const ushort_t* __restrict__ Bt,
                   const float* __restrict__ bias,
                   ushort_t* __restrict__ q, ushort_t* __restrict__ kk,
                   ushort_t* __restrict__ v) {
    const int M = MROWS, K = DIM;
    __shared__ ushort_t Asm[128 * 32];   // 8 KB
    __shared__ ushort_t Bsm[128 * 32];   // 8 KB
    const int tid  = threadIdx.x;
    const int wave = tid >> 6;
    const int lane = tid & 63;
    const int row0 = blockIdx.y * 128;
    const int col0 = blockIdx.x * 128;
    const int wm = wave >> 1, wn = wave & 1;
    const int q4 = lane >> 4, l15 = lane & 15;
    const int slotg = (lane & 3) ^ ((lane >> 3) & 3);  // staging source slot
    const int swz   = (l15 >> 1) & 3;                  // read-side row xor

    f32x4 acc[4][4];
    #pragma unroll
    for (int i = 0; i < 4; ++i)
        #pragma unroll
        for (int j = 0; j < 4; ++j) acc[i][j] = (f32x4){0.f, 0.f, 0.f, 0.f};

    for (int kt = 0; kt < K; kt += 32) {
        #pragma unroll
        for (int r = 0; r < 2; ++r) {
            int seg = r * 4 + wave;
            int rit = seg * 16 + (lane >> 2);
            int grow = min(row0 + rit, M - 1);
            const ushort_t* gp = A + (size_t)grow * K + kt + slotg * 8;
            gl2lds16(gp, &Asm[seg * 512]);
        }
        #pragma unroll
        for (int r = 0; r < 2; ++r) {
            int seg = r * 4 + wave;
            int nit = seg * 16 + (lane >> 2);
            const ushort_t* gp = Bt + (size_t)(col0 + nit) * K + kt + slotg * 8;
            gl2lds16(gp, &Bsm[seg * 512]);
        }
        __syncthreads();
        s16x8 af[4], bfr[4];
        #pragma unroll
        for (int mi = 0; mi < 4; ++mi)
            af[mi] = *(const s16x8*)&Asm[(wm * 64 + mi * 16 + l15) * 32
                                         + ((q4 ^ swz) * 8)];
        #pragma unroll
        for (int ni = 0; ni < 4; ++ni)
            bfr[ni] = *(const s16x8*)&Bsm[(wn * 64 + ni * 16 + l15) * 32
                                          + ((q4 ^ swz) * 8)];
        #pragma unroll
        for (int mi = 0; mi < 4; ++mi)
            #pragma unroll
            for (int ni = 0; ni < 4; ++ni)
                acc[mi][ni] = __builtin_amdgcn_mfma_f32_16x16x32_bf16(
                    af[mi], bfr[ni], acc[mi][ni], 0, 0, 0);
        __syncthreads();
    }
    int colbase = col0 + wn * 64;
    int seg = colbase / DIM;
    int csub = colbase - seg * DIM;
    ushort_t* outp = (seg == 0) ? q : (seg == 1) ? kk : v;
    #pragma unroll
    for (int mi = 0; mi < 4; ++mi) {
        #pragma unroll
        for (int ni = 0; ni < 4; ++ni) {
            int gcol = colbase + ni * 16 + l15;
            int col  = csub + ni * 16 + l15;
            float bb = bias[gcol];
            #pragma unroll
            for (int j = 0; j < 4; ++j) {
                int row = row0 + wm * 64 + mi * 16 + q4 * 4 + j;
                if (row < M)
                    outp[(size_t)row * DIM + col] = f2bf(acc[mi][ni][j] + bb);
            }
        }
    }
}

// ---------------------------------------------------------------------------
// K6: out GEMM via MFMA. A = o bf16, Bt = W_out^T bf16, C fp32.
// Same swizzled-LDS structure as K1.
// ---------------------------------------------------------------------------
__global__ __launch_bounds__(256)
void gemm_out_mfma(const ushort_t* __restrict__ A, const ushort_t* __restrict__ Bt,
                   const float* __restrict__ bias, float* __restrict__ C) {
    const int M = MROWS, N = DIM, K = DIM;
    __shared__ ushort_t Asm[128 * 32];
    __shared__ ushort_t Bsm[128 * 32];
    const int tid  = threadIdx.x;
    const int wave = tid >> 6;
    const int lane = tid & 63;
    const int row0 = blockIdx.y * 128;
    const int col0 = blockIdx.x * 128;
    const int wm = wave >> 1, wn = wave & 1;
    const int q4 = lane >> 4, l15 = lane & 15;
    const int slotg = (lane & 3) ^ ((lane >> 3) & 3);
    const int swz   = (l15 >> 1) & 3;

    f32x4 acc[4][4];
    #pragma unroll
    for (int i = 0; i < 4; ++i)
        #pragma unroll
        for (int j = 0; j < 4; ++j) acc[i][j] = (f32x4){0.f, 0.f, 0.f, 0.f};

    for (int kt = 0; kt < K; kt += 32) {
        #pragma unroll
        for (int r = 0; r < 2; ++r) {
            int seg = r * 4 + wave;
            int rit = seg * 16 + (lane >> 2);
            int grow = min(row0 + rit, M - 1);
            const ushort_t* gp = A + (size_t)grow * K + kt + slotg * 8;
            gl2lds16(gp, &Asm[seg * 512]);
        }
        #pragma unroll
        for (int r = 0; r < 2; ++r) {
            int seg = r * 4 + wave;
            int nit = seg * 16 + (lane >> 2);
            const ushort_t* gp = Bt + (size_t)(col0 + nit) * K + kt + slotg * 8;
            gl2lds16(gp, &Bsm[seg * 512]);
        }
        __syncthreads();
        s16x8 af[4], bfr[4];
        #pragma unroll
        for (int mi = 0; mi < 4; ++mi)
            af[mi] = *(const s16x8*)&Asm[(wm * 64 + mi * 16 + l15) * 32
                                         + ((q4 ^ swz) * 8)];
        #pragma unroll
        for (int ni = 0; ni < 4; ++ni)
            bfr[ni] = *(const s16x8*)&Bsm[(wn * 64 + ni * 16 + l15) * 32
                                          + ((q4 ^ swz) * 8)];
        #pragma unroll
        for (int mi = 0; mi < 4; ++mi)
            #pragma unroll
            for (int ni = 0; ni < 4; ++ni)
                acc[mi][ni] = __builtin_amdgcn_mfma_f32_16x16x32_bf16(
                    af[mi], bfr[ni], acc[mi][ni], 0, 0, 0);
        __syncthreads();
    }
    #pragma unroll
    for (int mi = 0; mi < 4; ++mi) {
        #pragma unroll
        for (int ni = 0; ni < 4; ++ni) {
            int col = col0 + wn * 64 + ni * 16 + l15;
            float bb = bias[col];
            #pragma unroll
            for (int j = 0; j < 4; ++j) {
                int row = row0 + wm * 64 + mi * 16 + q4 * 4 + j;
                if (row < M)
                    C[(size_t)row * N + col] = acc[mi][ni][j] + bb;
            }
        }
    }
}

// ---------------------------------------------------------------------------
// K2: per-(b,c) softmax stats over 785 tokens of k
// ---------------------------------------------------------------------------
__global__ __launch_bounds__(256)
void softmax_stats_kernel(const bf16* __restrict__ k,
                          float* __restrict__ stat_m, float* __restrict__ stat_is) {
    int b = blockIdx.y;
    int c = blockIdx.x * 64 + threadIdx.x;
    int ty = threadIdx.y;
    const bf16* base = k + (size_t)b * NTOK * DIM + c;
    float m = -1e30f, s = 0.f;
    for (int n = ty; n < NTOK; n += 4) {
        float kv = __bfloat162float(base[(size_t)n * DIM]);
        float nm = fmaxf(m, kv);
        s = s * __expf(m - nm) + __expf(kv - nm);
        m = nm;
    }
    __shared__ float sm[4][64], ss[4][64];
    sm[ty][threadIdx.x] = m; ss[ty][threadIdx.x] = s;
    __syncthreads();
    if (ty == 0) {
        float M = sm[0][threadIdx.x];
        #pragma unroll
        for (int i = 1; i < 4; ++i) M = fmaxf(M, sm[i][threadIdx.x]);
        float S = 0.f;
        #pragma unroll
        for (int i = 0; i < 4; ++i) S += ss[i][threadIdx.x] * __expf(sm[i][threadIdx.x] - M);
        stat_m[b * DIM + c] = M;
        stat_is[b * DIM + c] = 1.f / S;
    }
}

// ---------------------------------------------------------------------------
// K3: attn[b,h,d,e] = sum_n softmax(k)[n,d] * v[n,e]
// ---------------------------------------------------------------------------
__global__ __launch_bounds__(256)
void attn_kernel(const bf16* __restrict__ k, const bf16* __restrict__ v,
                 const float* __restrict__ stat_m, const float* __restrict__ stat_is,
                 float* __restrict__ attn) {
    int h = blockIdx.x, b = blockIdx.y;
    int tx = threadIdx.x, ty = threadIdx.y;
    int t = ty * 16 + tx;
    __shared__ float ek[16][96], vv[16][96];
    __shared__ float smM[96], smIS[96];
    if (t < 96) { smM[t] = stat_m[b * DIM + h * HD + t]; smIS[t] = stat_is[b * DIM + h * HD + t]; }
    __syncthreads();
    float acc[6][6] = {};
    const bf16* kbase = k + (size_t)b * NTOK * DIM + h * HD;
    const bf16* vbase = v + (size_t)b * NTOK * DIM + h * HD;
    for (int n0 = 0; n0 < NTOK; n0 += 16) {
        #pragma unroll
        for (int i = 0; i < 6; ++i) {
            int idx = t + i * 256;
            int nl = idx / 96, c = idx % 96;
            int n = n0 + nl;
            float ekv = 0.f, vvv = 0.f;
            if (n < NTOK) {
                float kv = __bfloat162float(kbase[(size_t)n * DIM + c]);
                ekv = __expf(kv - smM[c]) * smIS[c];
                vvv = __bfloat162float(vbase[(size_t)n * DIM + c]);
            }
            ek[nl][c] = ekv; vv[nl][c] = vvv;
        }
        __syncthreads();
        #pragma unroll
        for (int nl = 0; nl < 16; ++nl) {
            float ka[6], vb[6];
            #pragma unroll
            for (int i = 0; i < 6; ++i) ka[i] = ek[nl][tx * 6 + i];
            #pragma unroll
            for (int j = 0; j < 6; ++j) vb[j] = vv[nl][ty * 6 + j];
            #pragma unroll
            for (int i = 0; i < 6; ++i)
                #pragma unroll
                for (int j = 0; j < 6; ++j)
                    acc[i][j] += ka[i] * vb[j];
        }
        __syncthreads();
    }
    float* abase = attn + ((size_t)(b * NH + h)) * HD * HD;
    #pragma unroll
    for (int i = 0; i < 6; ++i)
        #pragma unroll
        for (int j = 0; j < 6; ++j)
            abase[(size_t)(tx * 6 + i) * HD + ty * 6 + j] = acc[i][j];
}

// ---------------------------------------------------------------------------
// K4: CRPE depthwise conv, restructured for occupancy + branch-free taps.
// Block = (cgroup32, half, batch), 256 threads = 16 ch-pairs x 16 rows (14 used).
// LDS tile: [20 rows][34 px][32 ch] bf16, zero halo (R=3), row pad +16 elems
//   -> reads land bank = p + 8*rowgroup: 2 lanes/bank = free.
// Weights staged to LDS (broadcast reads). Inner loop: per ky load a 13-px
// segment once, slide across kx -> ~13 LDS reads/output px instead of 49,
// 14 independent FMA chains.
// ---------------------------------------------------------------------------
#define CRS 1104   // conv tile row stride in bf16 elems (34*32 + 16 pad)

template<int KS>
__device__ __forceinline__ void crpe_conv32(const ushort_t* __restrict__ vimg,
                                            const float* __restrict__ wsm,
                                            float b0, float b1,
                                            ushort_t* __restrict__ ob,
                                            int p, int yl, int y) {
    constexpr int R = KS / 2;
    const float* wA = wsm + (2 * p) * KS * KS;
    const float* wB = wA + KS * KS;
    #pragma unroll
    for (int xo = 0; xo < 28; xo += 7) {
        float a0[7], a1[7];
        #pragma unroll
        for (int u = 0; u < 7; ++u) { a0[u] = b0; a1[u] = b1; }
        #pragma unroll
        for (int ky = 0; ky < KS; ++ky) {
            const ushort_t* rp = vimg + (yl + ky - R + 3) * CRS
                                      + (xo - R + 3) * 32 + 2 * p;
            float2 seg[6 + KS];
            #pragma unroll
            for (int i = 0; i < 6 + KS; ++i)
                seg[i] = __bfloat1622float2(*(const __hip_bfloat162*)(rp + i * 32));
            #pragma unroll
            for (int kx = 0; kx < KS; ++kx) {
                float wa = wA[ky * KS + kx];
                float wb = wB[ky * KS + kx];
                #pragma unroll
                for (int u = 0; u < 7; ++u) {
                    a0[u] = fmaf(wa, seg[u + kx].x, a0[u]);
                    a1[u] = fmaf(wb, seg[u + kx].y, a1[u]);
                }
            }
        }
        #pragma unroll
        for (int u = 0; u < 7; ++u)
            *(__hip_bfloat162*)&ob[(size_t)(1 + y * GW + xo + u) * DIM + 2 * p] =
                __float22bfloat162_rn(make_float2(a0[u], a1[u]));
    }
}

__global__ __launch_bounds__(256)
void crpe_lds_kernel(const ushort_t* __restrict__ v,
                     const float* __restrict__ w3, const float* __restrict__ b3,
                     const float* __restrict__ w5, const float* __restrict__ b5,
                     const float* __restrict__ w7, const float* __restrict__ b7,
                     ushort_t* __restrict__ o) {
    __shared__ ushort_t vimg[20 * CRS];   // 44,160 B
    __shared__ float    wsm[32 * 49];     //  6,272 B
    const int cg  = blockIdx.x;    // 0..23, 32-channel group
    const int hf  = blockIdx.y;    // 0..1 image half (rows 0..13 / 14..27)
    const int b   = blockIdx.z;
    const int tid = threadIdx.x;
    const int c0  = cg * 32;

    const float* wsrc; const float* bsrc; int ks;
    if (c0 < 192)      { wsrc = w3 + c0 * 9;          bsrc = b3 + c0;         ks = 3; }
    else if (c0 < 480) { wsrc = w5 + (c0 - 192) * 25; bsrc = b5 + (c0 - 192); ks = 5; }
    else               { wsrc = w7 + (c0 - 480) * 49; bsrc = b7 + (c0 - 480); ks = 7; }
    const int ksq = ks * ks;

    // zero 3 out-of-image rows (full rows incl. pad): 3 x 138 chunks of 8
    const int zr0 = hf ? 17 : 0;
    for (int idx = tid; idx < 3 * 138; idx += 256) {
        int rr = idx / 138, cc = idx - rr * 138;
        *(s16x8*)&vimg[(zr0 + rr) * CRS + cc * 8] = (s16x8){0,0,0,0,0,0,0,0};
    }
    // zero x-halo of the 17 valid rows: chunks 0..11 (lxx 0..2) and 124..135 (lxx 31..33)
    for (int idx = tid; idx < 17 * 24; idx += 256) {
        int vr = idx / 24, cc = idx - vr * 24;
        int ly = hf ? vr : vr + 3;
        int ch = (cc < 12) ? cc : (112 + cc);
        *(s16x8*)&vimg[ly * CRS + ch * 8] = (s16x8){0,0,0,0,0,0,0,0};
    }
    // stage weights: 32*ksq consecutive floats (channels contiguous)
    for (int idx = tid; idx < 32 * ksq; idx += 256)
        wsm[idx] = wsrc[idx];
    // stage image: 17 rows x 28 px x 4 chunks (8 ch each)
    const ushort_t* vb = v + (size_t)b * NTOK * DIM + c0;
    const int gy0 = hf ? 11 : 0;
    for (int idx = tid; idx < 17 * 28 * 4; idx += 256) {
        int vr = idx / 112, rem = idx - vr * 112;
        int px = rem >> 2, c8 = rem & 3;
        int gy = gy0 + vr;
        int ly = hf ? vr : vr + 3;
        *(s16x8*)&vimg[ly * CRS + (px + 3) * 32 + c8 * 8] =
            *(const s16x8*)(vb + (size_t)(1 + gy * GW + px) * DIM + c8 * 8);
    }
    ushort_t* ob = o + (size_t)b * NTOK * DIM + c0;
    if (hf == 0 && tid < 32) ob[tid] = 0;   // CLS row: rp = 0
    __syncthreads();

    const int p  = tid & 15;       // channel pair 0..15
    const int yl = tid >> 4;       // row within half 0..15
    if (yl >= 14) return;
    const int y = hf * 14 + yl;    // global row
    float bb0 = bsrc[2 * p], bb1 = bsrc[2 * p + 1];
    if (ks == 3)      crpe_conv32<3>(vimg, wsm, bb0, bb1, ob, p, yl, y);
    else if (ks == 5) crpe_conv32<5>(vimg, wsm, bb0, bb1, ob, p, yl, y);
    else              crpe_conv32<7>(vimg, wsm, bb0, bb1, ob, p, yl, y);
}

// ---------------------------------------------------------------------------
// K5: o[b,n,h*96+e] = scale * sum_d q[n,d] attn[d,e] + q[n,e] * rp (in-place)
// ---------------------------------------------------------------------------
__global__ __launch_bounds__(256)
void combine_kernel(const bf16* __restrict__ q, const float* __restrict__ attn,
                    bf16* __restrict__ o) {
    int h = blockIdx.x;
    int n0 = blockIdx.y * 64;
    int b = blockIdx.z;
    int tx = threadIdx.x, ty = threadIdx.y;
    int t = ty * 16 + tx;
    __shared__ float as[96][96];
    __shared__ float qs[64][97];
    const float* abase = attn + ((size_t)(b * NH + h)) * HD * HD;
    #pragma unroll
    for (int i = 0; i < 36; ++i) {
        int idx = t + i * 256;
        as[idx / 96][idx % 96] = abase[idx];
    }
    const bf16* qbase = q + (size_t)b * NTOK * DIM + h * HD;
    #pragma unroll
    for (int i = 0; i < 24; ++i) {
        int idx = t + i * 256;
        int rr = idx / 96, cc = idx % 96;
        int n = n0 + rr;
        qs[rr][cc] = (n < NTOK) ? __bfloat162float(qbase[(size_t)n * DIM + cc]) : 0.f;
    }
    __syncthreads();
    float acc[4][6] = {};
    for (int d = 0; d < 96; ++d) {
        float qa[4], ab[6];
        #pragma unroll
        for (int i = 0; i < 4; ++i) qa[i] = qs[ty * 4 + i][d];
        #pragma unroll
        for (int j = 0; j < 6; ++j) ab[j] = as[d][tx * 6 + j];
        #pragma unroll
        for (int i = 0; i < 4; ++i)
            #pragma unroll
            for (int j = 0; j < 6; ++j)
                acc[i][j] += qa[i] * ab[j];
    }
    const float scale = 0.10206207261596575f;  // 96^-0.5
    bf16* obase = o + (size_t)b * NTOK * DIM + h * HD;
    #pragma unroll
    for (int i = 0; i < 4; ++i) {
        int n = n0 + ty * 4 + i;
        if (n >= NTOK) continue;
        #pragma unroll
        for (int j = 0; j < 6; ++j) {
            int e = tx * 6 + j;
            size_t oa = (size_t)n * DIM + e;
            float rp = __bfloat162float(obase[oa]);
            float qv = qs[ty * 4 + i][e];
            obase[oa] = __float2bfloat16(scale * acc[i][j] + qv * rp);
        }
    }
}

// ---------------------------------------------------------------------------
extern "C" void kernel_launch(void* const* d_in, const int* in_sizes, int n_in,
                              void* d_out, int out_size, void* d_ws, size_t ws_size,
                              hipStream_t stream) {
    const float* x     = (const float*)d_in[0];
    const float* W_qkv = (const float*)d_in[1];
    const float* b_qkv = (const float*)d_in[2];
    const float* W_out = (const float*)d_in[3];
    const float* b_out = (const float*)d_in[4];
    const float* w3    = (const float*)d_in[5];
    const float* cb3   = (const float*)d_in[6];
    const float* w5    = (const float*)d_in[7];
    const float* cb5   = (const float*)d_in[8];
    const float* w7    = (const float*)d_in[9];
    const float* cb7   = (const float*)d_in[10];
    float* out = (float*)d_out;

    ushort_t* q = (ushort_t*)d_ws;
    ushort_t* k = q + (size_t)MROWS * DIM;
    ushort_t* v = k + (size_t)MROWS * DIM;
    float* attn    = (float*)(v + (size_t)MROWS * DIM);
    float* stat_m  = attn + (size_t)BN * NH * HD * HD;
    float* stat_is = stat_m + (size_t)BN * DIM;
    ushort_t* Wqkvt = (ushort_t*)(stat_is + (size_t)BN * DIM);
    ushort_t* Wot   = Wqkvt + (size_t)QKVD * DIM;
    ushort_t* o = k;   // alias: k dead after attn_kernel

    // xb (bf16 x) aliases d_out: 38.6 MB <= out 77 MB fp32; dead before gemm_out.
    ushort_t* xb = (ushort_t*)d_out;

    transpose_bf16_kernel<<<dim3(QKVD / 32, DIM / 32), dim3(32, 8), 0, stream>>>(
        W_qkv, Wqkvt, DIM, QKVD);
    transpose_bf16_kernel<<<dim3(DIM / 32, DIM / 32), dim3(32, 8), 0, stream>>>(
        W_out, Wot, DIM, DIM);
    {
        int n8 = MROWS * DIM / 8;
        f32_to_bf16_kernel<<<dim3((n8 + 255) / 256), 256, 0, stream>>>(x, xb, n8);
    }
    gemm_qkv_mfma<<<dim3(QKVD / 128, (MROWS + 127) / 128), 256, 0, stream>>>(
        xb, Wqkvt, b_qkv, q, k, v);
    softmax_stats_kernel<<<dim3(12, BN), dim3(64, 4), 0, stream>>>(
        (const bf16*)k, stat_m, stat_is);
    attn_kernel<<<dim3(NH, BN), dim3(16, 16), 0, stream>>>(
        (const bf16*)k, (const bf16*)v, stat_m, stat_is, attn);
    crpe_lds_kernel<<<dim3(24, 2, BN), 256, 0, stream>>>(
        v, w3, cb3, w5, cb5, w7, cb7, o);
    combine_kernel<<<dim3(NH, 13, BN), dim3(16, 16), 0, stream>>>(
        (const bf16*)q, attn, (bf16*)o);
    gemm_out_mfma<<<dim3(DIM / 128, (MROWS + 127) / 128), 256, 0, stream>>>(
        o, Wot, b_out, out);
}

// Round 3
// 660.469 us; speedup vs baseline: 1.7996x; 1.1357x over previous
//
#include <hip/hip_runtime.h>
#include <hip/hip_bf16.h>
#include <math.h>

#define BN    32
#define NTOK  785
#define GH    28
#define GW    28
#define DIM   768
#define QKVD  2304
#define NH    8
#define HD    96
#define MROWS (BN*NTOK)   // 25120
#define NS    4           // attn token-split
#define NPC   197         // ceil(785/4)

typedef __hip_bfloat16 bf16;
typedef unsigned short ushort_t;
typedef short s16x8 __attribute__((ext_vector_type(8)));   // 8 bf16 = 4 VGPRs
typedef float f32x4 __attribute__((ext_vector_type(4)));   // MFMA acc

// ---------------------------------------------------------------------------
// helpers
// ---------------------------------------------------------------------------
__device__ __forceinline__ void gl2lds16(const void* g, void* l) {
    // 16B per lane, LDS dest = wave-uniform base + lane*16
    __builtin_amdgcn_global_load_lds(
        (__attribute__((address_space(1))) void*)const_cast<void*>(g),
        (__attribute__((address_space(3))) void*)l, 16, 0, 0);
}

__device__ __forceinline__ ushort_t f2bf(float f) {
    bf16 h = __float2bfloat16(f);
    return *(ushort_t*)&h;
}

// ---------------------------------------------------------------------------
// K-1: fp32 -> bf16 convert (x -> xb). 8 elems/thread, vectorized.
// ---------------------------------------------------------------------------
__global__ __launch_bounds__(256)
void f32_to_bf16_kernel(const float* __restrict__ in, ushort_t* __restrict__ out,
                        int n8) {
    int i = blockIdx.x * 256 + threadIdx.x;
    if (i >= n8) return;
    const float4* p = (const float4*)(in + (size_t)i * 8);
    float4 a = p[0], b = p[1];
    union { s16x8 v; __hip_bfloat162 h[4]; } r;
    r.h[0] = __float22bfloat162_rn(make_float2(a.x, a.y));
    r.h[1] = __float22bfloat162_rn(make_float2(a.z, a.w));
    r.h[2] = __float22bfloat162_rn(make_float2(b.x, b.y));
    r.h[3] = __float22bfloat162_rn(make_float2(b.z, b.w));
    *(s16x8*)(out + (size_t)i * 8) = r.v;
}

// ---------------------------------------------------------------------------
// K0: transpose-convert W[R][C] fp32 -> Wt[C][R] bf16
// ---------------------------------------------------------------------------
__global__ __launch_bounds__(256)
void transpose_bf16_kernel(const float* __restrict__ W, ushort_t* __restrict__ Wt,
                           int R, int C) {
    __shared__ float tile[32][33];
    int c0 = blockIdx.x * 32, r0 = blockIdx.y * 32;
    int tx = threadIdx.x, ty = threadIdx.y;   // 32 x 8
    #pragma unroll
    for (int i = 0; i < 4; ++i)
        tile[ty + i * 8][tx] = W[(size_t)(r0 + ty + i * 8) * C + c0 + tx];
    __syncthreads();
    #pragma unroll
    for (int i = 0; i < 4; ++i)
        Wt[(size_t)(c0 + ty + i * 8) * R + r0 + tx] = f2bf(tile[tx][ty + i * 8]);
}

// ---------------------------------------------------------------------------
// K1: qkv GEMM via MFMA. A = xb bf16 [M][768], Bt = W_qkv^T bf16 [2304][768].
// 128x128 tile, BK=32, 4 waves, 16x16x32 MFMA. XOR-swizzled LDS (see r0).
// ---------------------------------------------------------------------------
__global__ __launch_bounds__(256)
void gemm_qkv_mfma(const ushort_t* __restrict__ A, const ushort_t* __restrict__ Bt,
                   const float* __restrict__ bias,
                   ushort_t* __restrict__ q, ushort_t* __restrict__ kk,
                   ushort_t* __restrict__ v) {
    const int M = MROWS, K = DIM;
    __shared__ ushort_t Asm[128 * 32];   // 8 KB
    __shared__ ushort_t Bsm[128 * 32];   // 8 KB
    const int tid  = threadIdx.x;
    const int wave = tid >> 6;
    const int lane = tid & 63;
    const int row0 = blockIdx.y * 128;
    const int col0 = blockIdx.x * 128;
    const int wm = wave >> 1, wn = wave & 1;
    const int q4 = lane >> 4, l15 = lane & 15;
    const int slotg = (lane & 3) ^ ((lane >> 3) & 3);  // staging source slot
    const int swz   = (l15 >> 1) & 3;                  // read-side row xor

    f32x4 acc[4][4];
    #pragma unroll
    for (int i = 0; i < 4; ++i)
        #pragma unroll
        for (int j = 0; j < 4; ++j) acc[i][j] = (f32x4){0.f, 0.f, 0.f, 0.f};

    for (int kt = 0; kt < K; kt += 32) {
        #pragma unroll
        for (int r = 0; r < 2; ++r) {
            int seg = r * 4 + wave;
            int rit = seg * 16 + (lane >> 2);
            int grow = min(row0 + rit, M - 1);
            const ushort_t* gp = A + (size_t)grow * K + kt + slotg * 8;
            gl2lds16(gp, &Asm[seg * 512]);
        }
        #pragma unroll
        for (int r = 0; r < 2; ++r) {
            int seg = r * 4 + wave;
            int nit = seg * 16 + (lane >> 2);
            const ushort_t* gp = Bt + (size_t)(col0 + nit) * K + kt + slotg * 8;
            gl2lds16(gp, &Bsm[seg * 512]);
        }
        __syncthreads();
        s16x8 af[4], bfr[4];
        #pragma unroll
        for (int mi = 0; mi < 4; ++mi)
            af[mi] = *(const s16x8*)&Asm[(wm * 64 + mi * 16 + l15) * 32
                                         + ((q4 ^ swz) * 8)];
        #pragma unroll
        for (int ni = 0; ni < 4; ++ni)
            bfr[ni] = *(const s16x8*)&Bsm[(wn * 64 + ni * 16 + l15) * 32
                                          + ((q4 ^ swz) * 8)];
        #pragma unroll
        for (int mi = 0; mi < 4; ++mi)
            #pragma unroll
            for (int ni = 0; ni < 4; ++ni)
                acc[mi][ni] = __builtin_amdgcn_mfma_f32_16x16x32_bf16(
                    af[mi], bfr[ni], acc[mi][ni], 0, 0, 0);
        __syncthreads();
    }
    int colbase = col0 + wn * 64;
    int seg = colbase / DIM;
    int csub = colbase - seg * DIM;
    ushort_t* outp = (seg == 0) ? q : (seg == 1) ? kk : v;
    #pragma unroll
    for (int mi = 0; mi < 4; ++mi) {
        #pragma unroll
        for (int ni = 0; ni < 4; ++ni) {
            int gcol = colbase + ni * 16 + l15;
            int col  = csub + ni * 16 + l15;
            float bb = bias[gcol];
            #pragma unroll
            for (int j = 0; j < 4; ++j) {
                int row = row0 + wm * 64 + mi * 16 + q4 * 4 + j;
                if (row < M)
                    outp[(size_t)row * DIM + col] = f2bf(acc[mi][ni][j] + bb);
            }
        }
    }
}

// ---------------------------------------------------------------------------
// K6: out GEMM via MFMA. A = o bf16, Bt = W_out^T bf16, C fp32.
// Same swizzled-LDS structure as K1.
// ---------------------------------------------------------------------------
__global__ __launch_bounds__(256)
void gemm_out_mfma(const ushort_t* __restrict__ A, const ushort_t* __restrict__ Bt,
                   const float* __restrict__ bias, float* __restrict__ C) {
    const int M = MROWS, N = DIM, K = DIM;
    __shared__ ushort_t Asm[128 * 32];
    __shared__ ushort_t Bsm[128 * 32];
    const int tid  = threadIdx.x;
    const int wave = tid >> 6;
    const int lane = tid & 63;
    const int row0 = blockIdx.y * 128;
    const int col0 = blockIdx.x * 128;
    const int wm = wave >> 1, wn = wave & 1;
    const int q4 = lane >> 4, l15 = lane & 15;
    const int slotg = (lane & 3) ^ ((lane >> 3) & 3);
    const int swz   = (l15 >> 1) & 3;

    f32x4 acc[4][4];
    #pragma unroll
    for (int i = 0; i < 4; ++i)
        #pragma unroll
        for (int j = 0; j < 4; ++j) acc[i][j] = (f32x4){0.f, 0.f, 0.f, 0.f};

    for (int kt = 0; kt < K; kt += 32) {
        #pragma unroll
        for (int r = 0; r < 2; ++r) {
            int seg = r * 4 + wave;
            int rit = seg * 16 + (lane >> 2);
            int grow = min(row0 + rit, M - 1);
            const ushort_t* gp = A + (size_t)grow * K + kt + slotg * 8;
            gl2lds16(gp, &Asm[seg * 512]);
        }
        #pragma unroll
        for (int r = 0; r < 2; ++r) {
            int seg = r * 4 + wave;
            int nit = seg * 16 + (lane >> 2);
            const ushort_t* gp = Bt + (size_t)(col0 + nit) * K + kt + slotg * 8;
            gl2lds16(gp, &Bsm[seg * 512]);
        }
        __syncthreads();
        s16x8 af[4], bfr[4];
        #pragma unroll
        for (int mi = 0; mi < 4; ++mi)
            af[mi] = *(const s16x8*)&Asm[(wm * 64 + mi * 16 + l15) * 32
                                         + ((q4 ^ swz) * 8)];
        #pragma unroll
        for (int ni = 0; ni < 4; ++ni)
            bfr[ni] = *(const s16x8*)&Bsm[(wn * 64 + ni * 16 + l15) * 32
                                          + ((q4 ^ swz) * 8)];
        #pragma unroll
        for (int mi = 0; mi < 4; ++mi)
            #pragma unroll
            for (int ni = 0; ni < 4; ++ni)
                acc[mi][ni] = __builtin_amdgcn_mfma_f32_16x16x32_bf16(
                    af[mi], bfr[ni], acc[mi][ni], 0, 0, 0);
        __syncthreads();
    }
    #pragma unroll
    for (int mi = 0; mi < 4; ++mi) {
        #pragma unroll
        for (int ni = 0; ni < 4; ++ni) {
            int col = col0 + wn * 64 + ni * 16 + l15;
            float bb = bias[col];
            #pragma unroll
            for (int j = 0; j < 4; ++j) {
                int row = row0 + wm * 64 + mi * 16 + q4 * 4 + j;
                if (row < M)
                    C[(size_t)row * N + col] = acc[mi][ni][j] + bb;
            }
        }
    }
}

// ---------------------------------------------------------------------------
// K2: per-(b,c) softmax stats over 785 tokens of k
// ---------------------------------------------------------------------------
__global__ __launch_bounds__(256)
void softmax_stats_kernel(const bf16* __restrict__ k,
                          float* __restrict__ stat_m, float* __restrict__ stat_is) {
    int b = blockIdx.y;
    int c = blockIdx.x * 64 + threadIdx.x;
    int ty = threadIdx.y;
    const bf16* base = k + (size_t)b * NTOK * DIM + c;
    float m = -1e30f, s = 0.f;
    for (int n = ty; n < NTOK; n += 4) {
        float kv = __bfloat162float(base[(size_t)n * DIM]);
        float nm = fmaxf(m, kv);
        s = s * __expf(m - nm) + __expf(kv - nm);
        m = nm;
    }
    __shared__ float sm[4][64], ss[4][64];
    sm[ty][threadIdx.x] = m; ss[ty][threadIdx.x] = s;
    __syncthreads();
    if (ty == 0) {
        float M = sm[0][threadIdx.x];
        #pragma unroll
        for (int i = 1; i < 4; ++i) M = fmaxf(M, sm[i][threadIdx.x]);
        float S = 0.f;
        #pragma unroll
        for (int i = 0; i < 4; ++i) S += ss[i][threadIdx.x] * __expf(sm[i][threadIdx.x] - M);
        stat_m[b * DIM + c] = M;
        stat_is[b * DIM + c] = 1.f / S;
    }
}

// ---------------------------------------------------------------------------
// K3: attn_part[ns][b,h,d,e] = sum_{n in chunk ns} exp(k[n,d]-m_d) * v[n,e]
// Token-split 4-way for occupancy (was 1 block/CU -> 4). 32-token tiles.
// Rows padded to 98 floats: staging writes <=4-way banks, compute reads
// broadcast/2-way. 1/S folded into the reduce kernel (distributes over sum).
// ---------------------------------------------------------------------------
__global__ __launch_bounds__(256)
void attn_kernel(const bf16* __restrict__ k, const bf16* __restrict__ v,
                 const float* __restrict__ stat_m,
                 float* __restrict__ attn_part) {
    int h = blockIdx.x, b = blockIdx.y, ns = blockIdx.z;
    int tx = threadIdx.x, ty = threadIdx.y;
    int t = ty * 16 + tx;
    __shared__ float ek[32][98], vv[32][98];
    __shared__ float smM[96];
    if (t < 96) smM[t] = stat_m[b * DIM + h * HD + t];
    __syncthreads();
    float acc[6][6] = {};
    const bf16* kbase = k + (size_t)b * NTOK * DIM + h * HD;
    const bf16* vbase = v + (size_t)b * NTOK * DIM + h * HD;
    const int nlo = ns * NPC;
    const int nhi = min(NTOK, nlo + NPC);
    const int tl = t >> 3;          // token slot 0..31
    const int cg = (t & 7) * 12;    // channel 0,12,..,84
    for (int n0 = nlo; n0 < nhi; n0 += 32) {
        int n = n0 + tl;
        float2 tk[6], tv[6];
        if (n < nhi) {
            #pragma unroll
            for (int j = 0; j < 6; ++j) {
                float2 kf = __bfloat1622float2(
                    *(const __hip_bfloat162*)&kbase[(size_t)n * DIM + cg + 2 * j]);
                float2 vf = __bfloat1622float2(
                    *(const __hip_bfloat162*)&vbase[(size_t)n * DIM + cg + 2 * j]);
                tk[j].x = __expf(kf.x - smM[cg + 2 * j]);
                tk[j].y = __expf(kf.y - smM[cg + 2 * j + 1]);
                tv[j] = vf;
            }
        } else {
            #pragma unroll
            for (int j = 0; j < 6; ++j) {
                tk[j] = make_float2(0.f, 0.f);
                tv[j] = make_float2(0.f, 0.f);
            }
        }
        #pragma unroll
        for (int j = 0; j < 6; ++j) {
            *(float2*)&ek[tl][cg + 2 * j] = tk[j];
            *(float2*)&vv[tl][cg + 2 * j] = tv[j];
        }
        __syncthreads();
        #pragma unroll
        for (int nl = 0; nl < 32; ++nl) {
            float2 ka01 = *(const float2*)&ek[nl][tx * 6];
            float2 ka23 = *(const float2*)&ek[nl][tx * 6 + 2];
            float2 ka45 = *(const float2*)&ek[nl][tx * 6 + 4];
            float2 vb01 = *(const float2*)&vv[nl][ty * 6];
            float2 vb23 = *(const float2*)&vv[nl][ty * 6 + 2];
            float2 vb45 = *(const float2*)&vv[nl][ty * 6 + 4];
            float ka[6] = {ka01.x, ka01.y, ka23.x, ka23.y, ka45.x, ka45.y};
            float vb[6] = {vb01.x, vb01.y, vb23.x, vb23.y, vb45.x, vb45.y};
            #pragma unroll
            for (int i = 0; i < 6; ++i)
                #pragma unroll
                for (int j = 0; j < 6; ++j)
                    acc[i][j] += ka[i] * vb[j];
        }
        __syncthreads();
    }
    float* abase = attn_part + (size_t)ns * BN * NH * HD * HD
                 + ((size_t)(b * NH + h)) * HD * HD;
    #pragma unroll
    for (int i = 0; i < 6; ++i)
        #pragma unroll
        for (int j = 0; j < 6; ++j)
            abase[(size_t)(tx * 6 + i) * HD + ty * 6 + j] = acc[i][j];
}

// ---------------------------------------------------------------------------
// K3b: attn[b,h,d,e] = stat_is[b,h*96+d] * sum_s attn_part[s][b,h,d,e]
// ---------------------------------------------------------------------------
__global__ __launch_bounds__(256)
void attn_reduce_kernel(const float* __restrict__ part,
                        const float* __restrict__ stat_is,
                        float* __restrict__ attn) {
    const int TOT4 = BN * NH * HD * HD / 4;   // 589824
    int i = blockIdx.x * 256 + threadIdx.x;
    if (i >= TOT4) return;
    size_t base = (size_t)i * 4;
    int bh = (int)(base / (HD * HD));
    int d  = (int)((base / HD) % HD);
    float is = stat_is[(bh >> 3) * DIM + (bh & 7) * HD + d];
    const size_t PSZ = (size_t)BN * NH * HD * HD;
    float4 s = *(const float4*)&part[base];
    float4 p1 = *(const float4*)&part[PSZ + base];
    float4 p2 = *(const float4*)&part[2 * PSZ + base];
    float4 p3 = *(const float4*)&part[3 * PSZ + base];
    s.x = (s.x + p1.x + p2.x + p3.x) * is;
    s.y = (s.y + p1.y + p2.y + p3.y) * is;
    s.z = (s.z + p1.z + p2.z + p3.z) * is;
    s.w = (s.w + p1.w + p2.w + p3.w) * is;
    *(float4*)&attn[base] = s;
}

// ---------------------------------------------------------------------------
// K4: CRPE depthwise conv, restructured for occupancy + branch-free taps.
// ---------------------------------------------------------------------------
#define CRS 1104   // conv tile row stride in bf16 elems (34*32 + 16 pad)

template<int KS>
__device__ __forceinline__ void crpe_conv32(const ushort_t* __restrict__ vimg,
                                            const float* __restrict__ wsm,
                                            float b0, float b1,
                                            ushort_t* __restrict__ ob,
                                            int p, int yl, int y) {
    constexpr int R = KS / 2;
    const float* wA = wsm + (2 * p) * KS * KS;
    const float* wB = wA + KS * KS;
    #pragma unroll
    for (int xo = 0; xo < 28; xo += 7) {
        float a0[7], a1[7];
        #pragma unroll
        for (int u = 0; u < 7; ++u) { a0[u] = b0; a1[u] = b1; }
        #pragma unroll
        for (int ky = 0; ky < KS; ++ky) {
            const ushort_t* rp = vimg + (yl + ky - R + 3) * CRS
                                      + (xo - R + 3) * 32 + 2 * p;
            float2 seg[6 + KS];
            #pragma unroll
            for (int i = 0; i < 6 + KS; ++i)
                seg[i] = __bfloat1622float2(*(const __hip_bfloat162*)(rp + i * 32));
            #pragma unroll
            for (int kx = 0; kx < KS; ++kx) {
                float wa = wA[ky * KS + kx];
                float wb = wB[ky * KS + kx];
                #pragma unroll
                for (int u = 0; u < 7; ++u) {
                    a0[u] = fmaf(wa, seg[u + kx].x, a0[u]);
                    a1[u] = fmaf(wb, seg[u + kx].y, a1[u]);
                }
            }
        }
        #pragma unroll
        for (int u = 0; u < 7; ++u)
            *(__hip_bfloat162*)&ob[(size_t)(1 + y * GW + xo + u) * DIM + 2 * p] =
                __float22bfloat162_rn(make_float2(a0[u], a1[u]));
    }
}

__global__ __launch_bounds__(256)
void crpe_lds_kernel(const ushort_t* __restrict__ v,
                     const float* __restrict__ w3, const float* __restrict__ b3,
                     const float* __restrict__ w5, const float* __restrict__ b5,
                     const float* __restrict__ w7, const float* __restrict__ b7,
                     ushort_t* __restrict__ o) {
    __shared__ ushort_t vimg[20 * CRS];   // 44,160 B
    __shared__ float    wsm[32 * 49];     //  6,272 B
    const int cg  = blockIdx.x;    // 0..23, 32-channel group
    const int hf  = blockIdx.y;    // 0..1 image half (rows 0..13 / 14..27)
    const int b   = blockIdx.z;
    const int tid = threadIdx.x;
    const int c0  = cg * 32;

    const float* wsrc; const float* bsrc; int ks;
    if (c0 < 192)      { wsrc = w3 + c0 * 9;          bsrc = b3 + c0;         ks = 3; }
    else if (c0 < 480) { wsrc = w5 + (c0 - 192) * 25; bsrc = b5 + (c0 - 192); ks = 5; }
    else               { wsrc = w7 + (c0 - 480) * 49; bsrc = b7 + (c0 - 480); ks = 7; }
    const int ksq = ks * ks;

    const int zr0 = hf ? 17 : 0;
    for (int idx = tid; idx < 3 * 138; idx += 256) {
        int rr = idx / 138, cc = idx - rr * 138;
        *(s16x8*)&vimg[(zr0 + rr) * CRS + cc * 8] = (s16x8){0,0,0,0,0,0,0,0};
    }
    for (int idx = tid; idx < 17 * 24; idx += 256) {
        int vr = idx / 24, cc = idx - vr * 24;
        int ly = hf ? vr : vr + 3;
        int ch = (cc < 12) ? cc : (112 + cc);
        *(s16x8*)&vimg[ly * CRS + ch * 8] = (s16x8){0,0,0,0,0,0,0,0};
    }
    for (int idx = tid; idx < 32 * ksq; idx += 256)
        wsm[idx] = wsrc[idx];
    const ushort_t* vb = v + (size_t)b * NTOK * DIM + c0;
    const int gy0 = hf ? 11 : 0;
    for (int idx = tid; idx < 17 * 28 * 4; idx += 256) {
        int vr = idx / 112, rem = idx - vr * 112;
        int px = rem >> 2, c8 = rem & 3;
        int gy = gy0 + vr;
        int ly = hf ? vr : vr + 3;
        *(s16x8*)&vimg[ly * CRS + (px + 3) * 32 + c8 * 8] =
            *(const s16x8*)(vb + (size_t)(1 + gy * GW + px) * DIM + c8 * 8);
    }
    ushort_t* ob = o + (size_t)b * NTOK * DIM + c0;
    if (hf == 0 && tid < 32) ob[tid] = 0;   // CLS row: rp = 0
    __syncthreads();

    const int p  = tid & 15;       // channel pair 0..15
    const int yl = tid >> 4;       // row within half 0..15
    if (yl >= 14) return;
    const int y = hf * 14 + yl;    // global row
    float bb0 = bsrc[2 * p], bb1 = bsrc[2 * p + 1];
    if (ks == 3)      crpe_conv32<3>(vimg, wsm, bb0, bb1, ob, p, yl, y);
    else if (ks == 5) crpe_conv32<5>(vimg, wsm, bb0, bb1, ob, p, yl, y);
    else              crpe_conv32<7>(vimg, wsm, bb0, bb1, ob, p, yl, y);
}

// ---------------------------------------------------------------------------
// K5: o[b,n,h*96+e] = scale * sum_d q[n,d] attn[d,e] + q[n,e] * rp (in-place)
// ---------------------------------------------------------------------------
__global__ __launch_bounds__(256)
void combine_kernel(const bf16* __restrict__ q, const float* __restrict__ attn,
                    bf16* __restrict__ o) {
    int h = blockIdx.x;
    int n0 = blockIdx.y * 64;
    int b = blockIdx.z;
    int tx = threadIdx.x, ty = threadIdx.y;
    int t = ty * 16 + tx;
    __shared__ float as[96][96];
    __shared__ float qs[64][97];
    const float* abase = attn + ((size_t)(b * NH + h)) * HD * HD;
    #pragma unroll
    for (int i = 0; i < 36; ++i) {
        int idx = t + i * 256;
        as[idx / 96][idx % 96] = abase[idx];
    }
    const bf16* qbase = q + (size_t)b * NTOK * DIM + h * HD;
    #pragma unroll
    for (int i = 0; i < 24; ++i) {
        int idx = t + i * 256;
        int rr = idx / 96, cc = idx % 96;
        int n = n0 + rr;
        qs[rr][cc] = (n < NTOK) ? __bfloat162float(qbase[(size_t)n * DIM + cc]) : 0.f;
    }
    __syncthreads();
    float acc[4][6] = {};
    for (int d = 0; d < 96; ++d) {
        float qa[4], ab[6];
        #pragma unroll
        for (int i = 0; i < 4; ++i) qa[i] = qs[ty * 4 + i][d];
        #pragma unroll
        for (int j = 0; j < 6; ++j) ab[j] = as[d][tx * 6 + j];
        #pragma unroll
        for (int i = 0; i < 4; ++i)
            #pragma unroll
            for (int j = 0; j < 6; ++j)
                acc[i][j] += qa[i] * ab[j];
    }
    const float scale = 0.10206207261596575f;  // 96^-0.5
    bf16* obase = o + (size_t)b * NTOK * DIM + h * HD;
    #pragma unroll
    for (int i = 0; i < 4; ++i) {
        int n = n0 + ty * 4 + i;
        if (n >= NTOK) continue;
        #pragma unroll
        for (int j = 0; j < 6; ++j) {
            int e = tx * 6 + j;
            size_t oa = (size_t)n * DIM + e;
            float rp = __bfloat162float(obase[oa]);
            float qv = qs[ty * 4 + i][e];
            obase[oa] = __float2bfloat16(scale * acc[i][j] + qv * rp);
        }
    }
}

// ---------------------------------------------------------------------------
extern "C" void kernel_launch(void* const* d_in, const int* in_sizes, int n_in,
                              void* d_out, int out_size, void* d_ws, size_t ws_size,
                              hipStream_t stream) {
    const float* x     = (const float*)d_in[0];
    const float* W_qkv = (const float*)d_in[1];
    const float* b_qkv = (const float*)d_in[2];
    const float* W_out = (const float*)d_in[3];
    const float* b_out = (const float*)d_in[4];
    const float* w3    = (const float*)d_in[5];
    const float* cb3   = (const float*)d_in[6];
    const float* w5    = (const float*)d_in[7];
    const float* cb5   = (const float*)d_in[8];
    const float* w7    = (const float*)d_in[9];
    const float* cb7   = (const float*)d_in[10];
    float* out = (float*)d_out;

    ushort_t* q = (ushort_t*)d_ws;
    ushort_t* k = q + (size_t)MROWS * DIM;
    ushort_t* v = k + (size_t)MROWS * DIM;
    float* attn    = (float*)(v + (size_t)MROWS * DIM);
    float* stat_m  = attn + (size_t)BN * NH * HD * HD;
    float* stat_is = stat_m + (size_t)BN * DIM;
    ushort_t* Wqkvt = (ushort_t*)(stat_is + (size_t)BN * DIM);
    ushort_t* Wot   = Wqkvt + (size_t)QKVD * DIM;
    ushort_t* o = k;   // alias: k dead after attn_kernel

    // d_out scratch layout: xb (bf16 x, 38.58 MB) then attn_part (37.75 MB).
    // Both dead before gemm_out_mfma writes d_out (77.17 MB total). 
    ushort_t* xb = (ushort_t*)d_out;
    float* attn_part = (float*)d_out + (size_t)MROWS * DIM / 2;

    transpose_bf16_kernel<<<dim3(QKVD / 32, DIM / 32), dim3(32, 8), 0, stream>>>(
        W_qkv, Wqkvt, DIM, QKVD);
    transpose_bf16_kernel<<<dim3(DIM / 32, DIM / 32), dim3(32, 8), 0, stream>>>(
        W_out, Wot, DIM, DIM);
    {
        int n8 = MROWS * DIM / 8;
        f32_to_bf16_kernel<<<dim3((n8 + 255) / 256), 256, 0, stream>>>(x, xb, n8);
    }
    gemm_qkv_mfma<<<dim3(QKVD / 128, (MROWS + 127) / 128), 256, 0, stream>>>(
        xb, Wqkvt, b_qkv, q, k, v);
    softmax_stats_kernel<<<dim3(12, BN), dim3(64, 4), 0, stream>>>(
        (const bf16*)k, stat_m, stat_is);
    attn_kernel<<<dim3(NH, BN, NS), dim3(16, 16), 0, stream>>>(
        (const bf16*)k, (const bf16*)v, stat_m, attn_part);
    {
        int tot4 = BN * NH * HD * HD / 4;
        attn_reduce_kernel<<<dim3((tot4 + 255) / 256), 256, 0, stream>>>(
            attn_part, stat_is, attn);
    }
    crpe_lds_kernel<<<dim3(24, 2, BN), 256, 0, stream>>>(
        v, w3, cb3, w5, cb5, w7, cb7, o);
    combine_kernel<<<dim3(NH, 13, BN), dim3(16, 16), 0, stream>>>(
        (const bf16*)q, attn, (bf16*)o);
    gemm_out_mfma<<<dim3(DIM / 128, (MROWS + 127) / 128), 256, 0, stream>>>(
        o, Wot, b_out, out);
}